// Round 9
// baseline (210.100 us; speedup 1.0000x reference)
//
#include <hip/hip_runtime.h>

#define NEG (-1e9f)
constexpr int NCLS   = 21;
constexpr int NBOX   = 8732;
constexpr int MAXOUT = 5;
constexpr int CAP    = NBOX;          // worst-case candidates per batch
constexpr float IOU_THR  = 0.5f;
constexpr float CONF_THR = 0.5f;

// ---------------------------------------------------------------------------
// Pass 1: PURE STREAM. 4 boxes/thread, 25 aligned float4 loads, softmax
// max/argmax, one coalesced float4 store of score-or-NEG. No atomics, no
// divergence, no barriers -- nothing that can force a vmcnt(0) drain of the
// load stream. (Diagnostic split: R1-R8 fused this with the divergent
// atomic epilogue, whose returned-value wait drains all outstanding loads.)
// Score arithmetic identical to reference: argmax(probs)==argmax(logits)
// first-index ties; max prob = 1/sum(expf(x-max)) in reference order.
// ---------------------------------------------------------------------------
__global__ __launch_bounds__(128) void score_kernel(
        const float* __restrict__ logits,
        float4* __restrict__ score_out,   // BN/4 entries
        int BN) {
    const int q = blockIdx.x * 128 + threadIdx.x;     // quad index
    const int g = q * 4;
    if (g >= BN) return;

    float s_res[4];
    if (g + 3 < BN) {
        const float4* f4 = (const float4*)(logits + (long long)g * 25);
        float v[100];
#pragma unroll
        for (int k = 0; k < 25; k++) {
            float4 r = f4[k];
            v[4 * k + 0] = r.x; v[4 * k + 1] = r.y;
            v[4 * k + 2] = r.z; v[4 * k + 3] = r.w;
        }
#pragma unroll
        for (int j = 0; j < 4; j++) {
            const float* L = v + 25 * j;
            float m = L[4];
            int am = 0;
#pragma unroll
            for (int jj = 1; jj < NCLS; jj++) {
                float x = L[4 + jj];
                if (x > m) { m = x; am = jj; }
            }
            float sum = 0.f;
#pragma unroll
            for (int jj = 0; jj < NCLS; jj++) sum += expf(L[4 + jj] - m);
            float score = 1.0f / sum;
            s_res[j] = (am != 0) ? score : NEG;
        }
    } else {
#pragma unroll
        for (int j = 0; j < 4; j++) {
            if (g + j >= BN) { s_res[j] = NEG; continue; }
            const float* L = logits + (long long)(g + j) * 25;
            float m = L[4];
            int am = 0;
            for (int jj = 1; jj < NCLS; jj++) {
                float x = L[4 + jj];
                if (x > m) { m = x; am = jj; }
            }
            float sum = 0.f;
            for (int jj = 0; jj < NCLS; jj++) sum += expf(L[4 + jj] - m);
            float score = 1.0f / sum;
            s_res[j] = (am != 0) ? score : NEG;
        }
    }
    score_out[q] = make_float4(s_res[0], s_res[1], s_res[2], s_res[3]);
}

// ---------------------------------------------------------------------------
// Pass 2: SPARSE GATHER. Scan the 4.5 MB score array (coalesced float4);
// ~1% of boxes pass score > CONF_THR. Those re-read their 4 loc floats,
// decode with the exact reference expressions, find argmax class again
// (cheap: 21 scalar loads, rare), and compact via atomicAdd. Atomics now
// only stall ~11K sparse threads, not the 112 MB stream.
// Candidate filter correctness: only boxes with (class != 0 && score > 0.5)
// can appear in the output -- a selection with score <= 0.5 zeroes its slot
// and all later slots, so its suppression never matters.
// ---------------------------------------------------------------------------
__global__ __launch_bounds__(128) void gather_kernel(
        const float* __restrict__ logits,
        const float4* __restrict__ dbox4,
        const float4* __restrict__ score_in,
        float4* __restrict__ cand,
        int* __restrict__ cnt,
        int BN) {
    const int q = blockIdx.x * 128 + threadIdx.x;
    const int g = q * 4;
    if (g >= BN) return;
    float4 s4 = score_in[q];
    float sc[4] = { s4.x, s4.y, s4.z, s4.w };

#pragma unroll
    for (int j = 0; j < 4; j++) {
        const int idx = g + j;
        if (idx >= BN) continue;
        const float score = sc[j];
        if (!(score > CONF_THR)) continue;      // NEG (background) also fails

        const int n = idx % NBOX;
        const int b = idx / NBOX;
        const float* L = logits + (long long)idx * 25;

        // class argmax (first index on ties) -- recompute, rare path
        float m = L[4];
        int am = 0;
        for (int jj = 1; jj < NCLS; jj++) {
            float x = L[4 + jj];
            if (x > m) { m = x; am = jj; }
        }

        // decode (identical expression order to reference)
        float4 db = dbox4[n];
        float cy = (db.z + db.x) * 0.5f;
        float cx = (db.w + db.y) * 0.5f;
        float h  = db.z - db.x;
        float w  = db.w - db.y;
        float ncy = L[0] * h + cy;
        float ncx = L[1] * w + cx;
        float nh  = expf(L[2]) * h;
        float nw  = expf(L[3]) * w;
        float y1 = fminf(fmaxf(ncy - nh * 0.5f, 0.f), 1.f);
        float x1 = fminf(fmaxf(ncx - nw * 0.5f, 0.f), 1.f);
        float y2 = fminf(fmaxf(ncy + nh * 0.5f, 0.f), 1.f);
        float x2 = fminf(fmaxf(ncx + nw * 0.5f, 0.f), 1.f);

        int p = atomicAdd(&cnt[b], 1);
        if (p < CAP) {
            float4* c = cand + ((long long)b * CAP + p) * 2;
            c[0] = make_float4(y1, x1, y2, x2);
            c[1] = make_float4(score, (float)am, (float)n, 0.f);
        }
    }
}

// ---------------------------------------------------------------------------
// Phase 3: exact NMS, ONE WAVE per batch element, zero barriers (passed 3x).
// s_sc[i] is read and written only by lane i%64 (single-owner); cross-lane
// communication is shuffle-only. Selection order: (score desc, orig idx asc)
// == jnp.argmax semantics. Early break: remaining slots provably zeros.
// ---------------------------------------------------------------------------
__global__ __launch_bounds__(64) void nms_kernel(
        const float4* __restrict__ cand,
        const int* __restrict__ cnt,
        float* __restrict__ out) {
    const int b    = blockIdx.x;
    const int lane = threadIdx.x;
    __shared__ float s_sc[CAP];
    __shared__ float s_id[CAP];

    const int M = min(cnt[b], CAP);
    const float4* cb = cand + (long long)b * CAP * 2;
    float* o = out + (long long)b * MAXOUT * 6;

    for (int i = lane; i < M; i += 64) {
        float4 mrec = cb[i * 2 + 1];
        s_sc[i] = mrec.x;               // owner: lane i%64 == lane
        s_id[i] = mrec.z;
    }

    int k = 0;
    for (; k < MAXOUT; k++) {
        float bv = -INFINITY, boid = 3.0e38f;
        int bi = -1;
        for (int i = lane; i < M; i += 64) {
            float v = s_sc[i], oid = s_id[i];
            if (v > bv || (v == bv && oid < boid)) { bv = v; boid = oid; bi = i; }
        }
        for (int mm = 32; mm >= 1; mm >>= 1) {
            float v2 = __shfl_xor(bv,   mm, 64);
            float o2 = __shfl_xor(boid, mm, 64);
            int   i2 = __shfl_xor(bi,   mm, 64);
            if (v2 > bv || (v2 == bv && o2 < boid)) { bv = v2; boid = o2; bi = i2; }
        }
        if (bi < 0 || !(bv > CONF_THR)) break;   // this & later slots -> zeros

        float4 sb = cb[bi * 2];
        if (lane == 0) {
            float4 mm2 = cb[bi * 2 + 1];
            o[k * 6 + 0] = sb.x; o[k * 6 + 1] = sb.y;
            o[k * 6 + 2] = sb.z; o[k * 6 + 3] = sb.w;
            o[k * 6 + 4] = mm2.y; o[k * 6 + 5] = bv;
        }

        float a1 = (sb.z - sb.x) * (sb.w - sb.y);
        for (int i = lane; i < M; i += 64) {
            float4 c = cb[i * 2];
            float tly = fmaxf(sb.x, c.x);
            float tlx = fmaxf(sb.y, c.y);
            float bry = fminf(sb.z, c.z);
            float brx = fminf(sb.w, c.w);
            float wh0 = fmaxf(bry - tly, 0.f);
            float wh1 = fmaxf(brx - tlx, 0.f);
            float inter = wh0 * wh1;
            float a2 = (c.z - c.x) * (c.w - c.y);
            float iou = inter / (a1 + a2 - inter + 1e-12f);
            if (iou > IOU_THR) s_sc[i] = NEG;    // owner-only write
        }
    }
    for (int j = k * 6 + lane; j < MAXOUT * 6; j += 64) o[j] = 0.f;
}

extern "C" void kernel_launch(void* const* d_in, const int* in_sizes, int n_in,
                              void* d_out, int out_size, void* d_ws, size_t ws_size,
                              hipStream_t stream) {
    const float* logits = (const float*)d_in[0];
    const float4* dbox4 = (const float4*)d_in[1];
    float* out          = (float*)d_out;

    const int N  = in_sizes[1] / 4;           // 8732
    const int B  = in_sizes[0] / (N * 25);    // 128
    const int BN = B * N;
    const int nquad = (BN + 3) / 4;           // 279424

    // ws layout: [cnt: B ints][pad 16B][scores: nquad float4][cand: B*CAP*2 float4]
    char* wsp = (char*)d_ws;
    int* cnt = (int*)wsp;
    size_t off = ((size_t)B * sizeof(int) + 15) & ~(size_t)15;
    float4* scores = (float4*)(wsp + off);
    off += (size_t)nquad * sizeof(float4);
    float4* cand = (float4*)(wsp + off);

    hipMemsetAsync(cnt, 0, (size_t)B * sizeof(int), stream);
    const int nblocks = (nquad + 127) / 128;
    score_kernel<<<nblocks, 128, 0, stream>>>(logits, scores, BN);
    gather_kernel<<<nblocks, 128, 0, stream>>>(logits, dbox4, scores, cand, cnt, BN);
    nms_kernel<<<B, 64, 0, stream>>>(cand, cnt, out);
}